// Round 11
// baseline (154.145 us; speedup 1.0000x reference)
//
#include <hip/hip_runtime.h>
#include <hip/hip_bf16.h>
#include <stdint.h>

// MLP: hidden = X @ W1^T + b1 ; out = hidden @ W2^T + b2
// X [16384,2048] f32, W1 [512,2048], b1 [512], W2 [2048,512], b2 [2048]
// R14: R13's occupancy null (4 blocks/CU, bf16, no change) killed all
// scheduling theories. Surviving theory: gemm1 is L3->L2 refill-bound --
// gemm2's per-XCD source set (2 MB H-panels + 2 MB W2) = exactly L2, while
// gemm1's (16 A-panels = 8 MB + 2 MB W1) thrashes L2 and K-drift across the
// 4 bn-blocks re-fetches A slices from L3 (~270 MB through L3->L2).
// Fix: 64x512 tile (full N per block): A re-read factor 4 -> 1 (A read ONCE,
// streamed), only re-read operand is W1 (2 MB, L2-resident per XCD by
// construction). Grid 256 = 1 block/CU; 4 waves, each 64 rows x 128 cols
// (acc[4][8]); LDS 2 x (8K A + 64K B) = 144 KB dbuf; R12 single-barrier
// stage-before-compute loop. cast pass + gemm2 unchanged (controls).

typedef short bf16x8 __attribute__((ext_vector_type(8)));
typedef float f32x4 __attribute__((ext_vector_type(4)));

static __device__ __forceinline__ unsigned short f32_to_bf16_rne(float f) {
    unsigned int u = __float_as_uint(f);
    u += 0x7fffu + ((u >> 16) & 1u);
    return (unsigned short)(u >> 16);
}

// one kernel casts X, W1, W2 (f32 -> bf16), grid-stride over float4s
__global__ void cast_bf16_all(const float* __restrict__ x,
                              unsigned short* __restrict__ xo, int nx4,
                              const float* __restrict__ w1,
                              unsigned short* __restrict__ w1o,
                              const float* __restrict__ w2,
                              unsigned short* __restrict__ w2o, int nw4) {
    const int total = nx4 + 2 * nw4;
    const int stride = gridDim.x * blockDim.x;
    for (int i = blockIdx.x * blockDim.x + threadIdx.x; i < total; i += stride) {
        const float* in;
        unsigned short* out;
        int j;
        if (i < nx4) {
            in = x; out = xo; j = i;
        } else if (i < nx4 + nw4) {
            in = w1; out = w1o; j = i - nx4;
        } else {
            in = w2; out = w2o; j = i - nx4 - nw4;
        }
        float4 v = ((const float4*)in)[j];
        ushort4 o;
        o.x = f32_to_bf16_rne(v.x);
        o.y = f32_to_bf16_rne(v.y);
        o.z = f32_to_bf16_rne(v.z);
        o.w = f32_to_bf16_rne(v.w);
        ((ushort4*)out)[j] = o;
    }
}

#define GLOAD_LDS16(gsrc, ldst)                                              \
    __builtin_amdgcn_global_load_lds(                                        \
        (const __attribute__((address_space(1))) void*)(gsrc),               \
        (__attribute__((address_space(3))) void*)(ldst), 16, 0, 0)

// ---------------------------------------------------------------------------
// GEMM1 (bf16, full-N tile): H[16384][512] = Xbf[16384][2048] @ W1bf^T + b1
// 64(M) x 512(N) tile, 256 thr = 4 waves; wave w owns 64 rows x cols
// [128w, 128w+128) -> acc[4][8]. BK=64, NSTEP=32.
// LDS (dbuf): A [64][64] bf16 = 8 KB, B [512][64] bf16 = 64 KB -> 144 KB.
// A is read from L2/L3 exactly ONCE (no bn multiplicity); W1 = 2 MB is
// L2-resident per XCD. Rows are 128 B = 8 units; phys = logical ^ (row&7),
// staged via pre-swizzled source column (involution, rule #21).
// Loop: stage(t+1 -> buf^1) BEFORE compute(buf); one __syncthreads/step.
// ---------------------------------------------------------------------------
__global__ __launch_bounds__(256)
void gemm1_wide(const unsigned short* __restrict__ A,
                const unsigned short* __restrict__ Bt,
                const float* __restrict__ bias,
                unsigned short* __restrict__ H) {
    constexpr int N = 512, Kd = 2048, BK = 64, NSTEP = Kd / BK;  // 32 steps

    __shared__ __align__(16) unsigned short ldsA[2][64 * BK];   // 2 x 8 KB
    __shared__ __align__(16) unsigned short ldsB[2][512 * BK];  // 2 x 64 KB

    const int tid  = threadIdx.x;
    const int lane = tid & 63;
    const int w    = tid >> 6;   // 0..3 : 128-col quarter

    // XCD swizzle: nwg = 256 = 8 * 32 -> XCD x gets rows [32x*64, ...)
    const int bid = blockIdx.x;
    const int swz = ((bid & 7) << 5) + (bid >> 3);
    const int brow = swz << 6;

    const int lrow = lane & 15;
    const int ku   = lane >> 4;
    const int rx   = lrow & 7;

    // staging geometry (shared): thread t -> row chunk (t>>3), unit t&7,
    // pre-swizzled source unit = (t&7) ^ ((t>>3)&7)
    const int srow = tid >> 3;                       // 0..31
    const int sgu  = (tid & 7) ^ (srow & 7);

    f32x4 acc[4][8] = {};

    auto stage = [&](int k0, int pb) {
#pragma unroll
        for (int i = 0; i < 2; ++i) {               // A: 64 rows
            const int row = i * 32 + srow;
            const char* sa =
                (const char*)(A + (size_t)(brow + row) * Kd + k0) + (sgu << 4);
            GLOAD_LDS16(sa, (char*)ldsA[pb] + i * 4096 + tid * 16);
        }
#pragma unroll
        for (int i = 0; i < 16; ++i) {              // B: 512 rows (all of W1)
            const int row = i * 32 + srow;
            const char* sb =
                (const char*)(Bt + (size_t)row * Kd + k0) + (sgu << 4);
            GLOAD_LDS16(sb, (char*)ldsB[pb] + i * 4096 + tid * 16);
        }
    };
    auto compute = [&](int pb) {
#pragma unroll
        for (int kk = 0; kk < 2; ++kk) {
            const int un = ((ku + (kk << 2)) ^ rx) << 4;
            bf16x8 a[4], b[8];
#pragma unroll
            for (int m = 0; m < 4; ++m)
                a[m] = *(const bf16x8*)((const char*)ldsA[pb] +
                       ((m << 4) + lrow) * 128 + un);
#pragma unroll
            for (int n = 0; n < 8; ++n)
                b[n] = *(const bf16x8*)((const char*)ldsB[pb] +
                       ((w << 7) + (n << 4) + lrow) * 128 + un);
#pragma unroll
            for (int m = 0; m < 4; ++m)
#pragma unroll
                for (int n = 0; n < 8; ++n)
                    acc[m][n] = __builtin_amdgcn_mfma_f32_16x16x32_bf16(
                        a[m], b[n], acc[m][n], 0, 0, 0);
        }
    };

    // prologue: tile 0 -> buf0
    stage(0, 0);
    __syncthreads();

#pragma unroll 1
    for (int t = 0; t < NSTEP; ++t) {
        if (t + 1 < NSTEP) stage((t + 1) * BK, (t + 1) & 1);  // issue-first
        compute(t & 1);
        __syncthreads();   // drains stage(t+1), overlapped by compute; also
                           // protects buf reuse at t+2
    }

    // epilogue: C/D layout col = lane&15, row = (lane>>4)*4 + j  [m89]
    const int r0 = (lane >> 4) << 2;
#pragma unroll
    for (int n = 0; n < 8; ++n) {
        const int col = (w << 7) + (n << 4) + lrow;
        const float bb = bias[col];
#pragma unroll
        for (int m = 0; m < 4; ++m)
#pragma unroll
            for (int j = 0; j < 4; ++j) {
                const int row = brow + (m << 4) + r0 + j;
                H[(size_t)row * N + col] = f32_to_bf16_rne(acc[m][n][j] + bb);
            }
    }
}

// ---------------------------------------------------------------------------
// GEMM2: out[16384][2048] f32 = Hbf[16384][512] @ W2bf[2048][512]^T + b2
// 128x128 tile, 256 thr, BK=64, single-buffered 32 KB -> 5 blocks/CU.
// grid = 128*16 = 2048 blocks, chunked XCD swizzle (q=256). (unchanged)
// ---------------------------------------------------------------------------
__global__ __launch_bounds__(256)
void gemm2(const unsigned short* __restrict__ A,
           const unsigned short* __restrict__ Bt,
           const float* __restrict__ bias,
           float* __restrict__ C) {
    constexpr int N = 2048, Kd = 512, BK = 64, NSTEP = Kd / BK;  // 8 steps

    __shared__ __align__(16) unsigned short ldsA[128 * BK];  // 16 KB
    __shared__ __align__(16) unsigned short ldsB[128 * BK];  // 16 KB

    const int tid  = threadIdx.x;
    const int lane = tid & 63;
    const int wid  = tid >> 6;
    const int wr   = wid >> 1;
    const int wc   = wid & 1;

    const int bid = blockIdx.x;
    const int swz = ((bid & 7) << 8) + (bid >> 3);   // nwg=2048, q=256
    const int bn  = swz & 15;
    const int bm  = swz >> 4;
    const int brow = bm << 7;
    const int bcol = bn << 7;

    const int lrow = lane & 15;
    const int ku   = lane >> 4;
    const int rx   = lrow & 7;

    const int srow = tid >> 3;
    const int sgu  = (tid & 7) ^ (srow & 7);

    f32x4 acc[4][4] = {};

    auto stage = [&](int k0) {
#pragma unroll
        for (int i = 0; i < 4; ++i) {
            const int row = i * 32 + srow;
            const char* sa =
                (const char*)(A + (size_t)(brow + row) * Kd + k0) + (sgu << 4);
            const char* sb =
                (const char*)(Bt + (size_t)(bcol + row) * Kd + k0) + (sgu << 4);
            GLOAD_LDS16(sa, (char*)ldsA + i * 4096 + tid * 16);
            GLOAD_LDS16(sb, (char*)ldsB + i * 4096 + tid * 16);
        }
    };
    auto compute = [&]() {
#pragma unroll
        for (int kk = 0; kk < 2; ++kk) {
            const int un = ((ku + (kk << 2)) ^ rx) << 4;
            bf16x8 a[4], b[4];
#pragma unroll
            for (int m = 0; m < 4; ++m)
                a[m] = *(const bf16x8*)((const char*)ldsA +
                       ((wr << 6) + (m << 4) + lrow) * 128 + un);
#pragma unroll
            for (int n = 0; n < 4; ++n)
                b[n] = *(const bf16x8*)((const char*)ldsB +
                       ((wc << 6) + (n << 4) + lrow) * 128 + un);
#pragma unroll
            for (int m = 0; m < 4; ++m)
#pragma unroll
                for (int n = 0; n < 4; ++n)
                    acc[m][n] = __builtin_amdgcn_mfma_f32_16x16x32_bf16(
                        a[m], b[n], acc[m][n], 0, 0, 0);
        }
    };

    stage(0);
    __syncthreads();

    for (int t = 0; t < NSTEP; ++t) {
        compute();
        if (t + 1 < NSTEP) {
            __syncthreads();
            stage((t + 1) * BK);
            __syncthreads();
        }
    }

    const int r0 = (lane >> 4) << 2;
#pragma unroll
    for (int n = 0; n < 4; ++n) {
        const int col = bcol + (wc << 6) + (n << 4) + lrow;
        const float bb = bias[col];
#pragma unroll
        for (int m = 0; m < 4; ++m)
#pragma unroll
            for (int j = 0; j < 4; ++j) {
                const int row = brow + (wr << 6) + (m << 4) + r0 + j;
                C[(size_t)row * N + col] = acc[m][n][j] + bb;
            }
    }
}

extern "C" void kernel_launch(void* const* d_in, const int* in_sizes, int n_in,
                              void* d_out, int out_size, void* d_ws, size_t ws_size,
                              hipStream_t stream) {
    const float* X  = (const float*)d_in[0];   // [16384][2048]
    const float* W1 = (const float*)d_in[1];   // [512][2048]
    const float* b1 = (const float*)d_in[2];   // [512]
    const float* W2 = (const float*)d_in[3];   // [2048][512]
    const float* b2 = (const float*)d_in[4];   // [2048]

    const int B = 16384, M = 2048, Kd = 512;

    // workspace: W1bf (2MB), W2bf (2MB), Hbf (16.8MB), Xbf (64MB)
    char* ws = (char*)d_ws;
    unsigned short* W1bf = (unsigned short*)ws;
    unsigned short* W2bf = W1bf + (size_t)Kd * M;
    unsigned short* Hbf  = W2bf + (size_t)M * Kd;
    unsigned short* Xbf  = Hbf + (size_t)B * Kd;

    const int nx4 = B * M / 4;        // 8,388,608 float4s
    const int nw4 = Kd * M / 4;       //   262,144 float4s each

    cast_bf16_all<<<4096, 256, 0, stream>>>(X, Xbf, nx4, W1, W1bf, W2, W2bf,
                                            nw4);

    gemm1_wide<<<B / 64, 256, 0, stream>>>(Xbf, W1bf, b1, Hbf);
    gemm2<<<(B / 128) * (M / 128), 256, 0, stream>>>(Hbf, W2bf, b2,
                                                     (float*)d_out);
}